// Round 15
// baseline (223.115 us; speedup 1.0000x reference)
//
#include <hip/hip_runtime.h>
#include <math.h>

#define MD   512
#define NH   8
#define DH   64
#define SEQ  4096

typedef _Float16 f16x8 __attribute__((ext_vector_type(8)));
typedef _Float16 f16x4 __attribute__((ext_vector_type(4)));
typedef float    f32x4 __attribute__((ext_vector_type(4)));

#define LDSTR 72   // f16 row stride: 144 B, 16B-aligned, 2-way bank aliasing max
#define KMK   (-1.0e9f * 1.4426950408889634f)   // mask -> exp2-domain bias
#define KSC   (0.125f * 1.4426950408889634f)    // 1/sqrt(64) * log2(e)

// pack two f32 -> one u32 of two f16 (RTZ)
static __device__ __forceinline__ unsigned int pkf16(float a, float b) {
    auto t = __builtin_amdgcn_cvt_pkrtz(a, b);   // __fp16 ext_vector(2)
    return __builtin_bit_cast(unsigned int, t);
}
// in-place lane-group swaps (gfx950): both operands modified
static __device__ __forceinline__ void pl32_swap(unsigned int& a, unsigned int& b) {
    asm("v_permlane32_swap_b32 %0, %1" : "+v"(a), "+v"(b));
}
static __device__ __forceinline__ void pl16_swap(unsigned int& a, unsigned int& b) {
    asm("v_permlane16_swap_b32 %0, %1" : "+v"(a), "+v"(b));
}

// ---------------------------------------------------------------- prep_wt (round-5 proven):
// transpose wq/wk/wv (f32 [k][n]) -> WT3 f16 [n][k] and wo -> woT.
__global__ __launch_bounds__(256)
void prep_wt(const float* __restrict__ wq, const float* __restrict__ wk,
             const float* __restrict__ wv, const float* __restrict__ wo,
             _Float16* __restrict__ WT3, _Float16* __restrict__ woT)
{
    __shared__ float t[64][65];
    const int z = blockIdx.z;
    const float* W = (z == 0) ? wq : (z == 1) ? wk : (z == 2) ? wv : wo;
    _Float16* WTz = (z < 3) ? (WT3 + (size_t)z * MD * MD) : woT;
    const int k0 = blockIdx.x * 64, n0 = blockIdx.y * 64;
    const int c = threadIdx.x & 63, rbase = (threadIdx.x >> 6) * 16;
#pragma unroll
    for (int i = 0; i < 16; ++i)
        t[rbase + i][c] = W[(size_t)(k0 + rbase + i) * MD + n0 + c];
    __syncthreads();
#pragma unroll
    for (int i = 0; i < 16; ++i)
        WTz[(size_t)(n0 + rbase + i) * MD + k0 + c] = (_Float16)t[c][rbase + i];
}

// ---------------------------------------------------------------- proj3m:
// Grid (SEQ/64, MD/64, 4). z=0: q -> Qh; z=1: k -> Kh; z=2: v -> VTh [MD][SEQ];
// z=3: mask scan -> per-tile nonzero FLAG (wave-autonomous, barrier-free,
//      float4 reads) + permuted maskP emitted ONLY for nonzero tiles (rare path).
// 1-term GEMM slices (round-13 proven).
__global__ __launch_bounds__(256)
void proj3m(const float* __restrict__ q, const float* __restrict__ k,
            const float* __restrict__ v, const float* __restrict__ mask,
            const _Float16* __restrict__ WT3,
            _Float16* __restrict__ Qh,
            _Float16* __restrict__ Kh, _Float16* __restrict__ VTh,
            _Float16* __restrict__ maskP, unsigned char* __restrict__ mflag)
{
    __shared__ _Float16 SH[2 * 64 * LDSTR];   // GEMM: Ash|Wsh; mask: 4x wave patch 32*LDSTR

    const int z   = blockIdx.z;
    const int tid = threadIdx.x;
    const int ln   = tid & 15;
    const int quad = (tid & 63) >> 4;
    const int wv_  = tid >> 6;

    if (z == 3) {   // ---- mask scan: ONE WAVE per 128x64 idx-tile, no barriers
        const int idx = ((blockIdx.y * 64 + blockIdx.x) << 2) + wv_;   // 0..2047
        const int bx  = idx >> 6;     // 128-row tile
        const int tg  = idx & 63;     // 64-col tile
        const int l16 = tid & 15;     // 16 lanes span the 64 cols (float4 each)
        const int r4  = (tid & 63) >> 4;   // 4 row-slots per load batch
        const float* basep = mask + (size_t)(bx * 128) * SEQ + tg * 64 + l16 * 4;

        // common path: scan 128 rows with float4 loads (8 per section), flag only
        int nz = 0;
#pragma unroll 1
        for (int sec = 0; sec < 4; ++sec) {
            float4 mm[8];
#pragma unroll
            for (int r = 0; r < 8; ++r)
                mm[r] = *(const float4*)(basep + (size_t)(sec * 32 + r * 4 + r4) * SEQ);
#pragma unroll
            for (int r = 0; r < 8; ++r)
                nz |= (mm[r].x != 0.f) | (mm[r].y != 0.f) |
                      (mm[r].z != 0.f) | (mm[r].w != 0.f);
        }
        const bool has = (__ballot(nz) != 0ULL);
        if ((tid & 63) == 0) mflag[idx] = has ? 1 : 0;

        if (has) {   // rare path: emit permuted maskP via wave-private LDS patch
            _Float16* T = SH + wv_ * (32 * LDSTR);   // 32x72 f16 patch
            _Float16* outp = maskP + (size_t)idx * 8192;
#pragma unroll 1
            for (int sec = 0; sec < 4; ++sec) {   // sec = contract's wave-section
#pragma unroll
                for (int r = 0; r < 8; ++r) {
                    const int rr = r * 4 + r4;    // row within section
                    const float4 mm = *(const float4*)(basep + (size_t)(sec * 32 + rr) * SEQ);
                    f16x4 hv;
                    hv[0] = (_Float16)(mm.x * KMK); hv[1] = (_Float16)(mm.y * KMK);
                    hv[2] = (_Float16)(mm.z * KMK); hv[3] = (_Float16)(mm.w * KMK);
                    *(f16x4*)&T[rr * LDSTR + l16 * 4] = hv;
                }
                asm volatile("s_waitcnt lgkmcnt(0)" ::: "memory");   // wave-private
                __builtin_amdgcn_sched_barrier(0);
#pragma unroll
                for (int c = 0; c < 4; ++c) {
                    const int rho = (c >> 1) * 16 + l16;       // row within section
                    const int cb  = (c & 1) * 32 + r4 * 4;     // r4 == contract quad
                    const f16x4 lo = *(const f16x4*)&T[rho * LDSTR + cb];
                    const f16x4 hi = *(const f16x4*)&T[rho * LDSTR + cb + 16];
                    f16x8 hv;
                    hv[0] = lo[0]; hv[1] = lo[1]; hv[2] = lo[2]; hv[3] = lo[3];
                    hv[4] = hi[0]; hv[5] = hi[1]; hv[6] = hi[2]; hv[7] = hi[3];
                    *(f16x8*)&outp[(size_t)c * 2048 +
                                   (size_t)(sec * 64 + (tid & 63)) * 8] = hv;
                }
                asm volatile("s_waitcnt lgkmcnt(0)" ::: "memory");   // reads done
                __builtin_amdgcn_sched_barrier(0);
            }
        }
        return;
    }

    _Float16* Ash = SH;
    _Float16* Wsh = SH + 64 * LDSTR;

    const float* A32 = (z == 0) ? q : (z == 1) ? k : v;
    const _Float16* WTz = WT3 + (size_t)z * MD * MD;

    const int wr   = wv_ * 16;
    const int m0   = blockIdx.x * 64;
    const int n0   = blockIdx.y * 64;
    const int srow = tid >> 2;          // 0..63
    const int scol = (tid & 3) << 4;    // 0,16,32,48

    f32x4 acc[4] = {{0.f,0.f,0.f,0.f},{0.f,0.f,0.f,0.f},
                    {0.f,0.f,0.f,0.f},{0.f,0.f,0.f,0.f}};

    for (int k0 = 0; k0 < MD; k0 += 64) {
        const size_t ga  = (size_t)(m0 + srow) * MD + k0 + scol;
        const size_t gwt = (size_t)(n0 + srow) * MD + k0 + scol;
        float a[16];
#pragma unroll
        for (int j = 0; j < 4; ++j) {
            const float4 xa = *(const float4*)&A32[ga + j * 4];
            a[j*4+0] = xa.x; a[j*4+1] = xa.y; a[j*4+2] = xa.z; a[j*4+3] = xa.w;
        }
        const f16x8 w0 = *(const f16x8*)&WTz[gwt];
        const f16x8 w1 = *(const f16x8*)&WTz[gwt + 8];
        f16x8 ah[2];
#pragma unroll
        for (int half = 0; half < 2; ++half)
#pragma unroll
            for (int j = 0; j < 8; ++j)
                ah[half][j] = (_Float16)a[half * 8 + j];
        __syncthreads();
        *(f16x8*)&Ash[srow * LDSTR + scol]     = ah[0];
        *(f16x8*)&Ash[srow * LDSTR + scol + 8] = ah[1];
        *(f16x8*)&Wsh[srow * LDSTR + scol]     = w0;   // [n][k], pre-transposed
        *(f16x8*)&Wsh[srow * LDSTR + scol + 8] = w1;
        __syncthreads();

#pragma unroll
        for (int ks = 0; ks < 2; ++ks) {
            const f16x8 fa = *(f16x8*)&Ash[(wr + ln) * LDSTR + ks * 32 + quad * 8];
#pragma unroll
            for (int nt = 0; nt < 4; ++nt) {
                const f16x8 fb = *(f16x8*)&Wsh[(nt * 16 + ln) * LDSTR + ks * 32 + quad * 8];
                acc[nt] = __builtin_amdgcn_mfma_f32_16x16x32_f16(fa, fb, acc[nt], 0, 0, 0);
            }
        }
    }

    if (z == 2) {   // V hi, transposed [MD][SEQ]
#pragma unroll
        for (int nt = 0; nt < 4; ++nt)
#pragma unroll
            for (int r = 0; r < 4; ++r)
                VTh[(size_t)(n0 + nt * 16 + ln) * SEQ + m0 + wr + quad * 4 + r] =
                    (_Float16)acc[nt][r];
    } else if (z == 1) {   // K hi only
#pragma unroll
        for (int nt = 0; nt < 4; ++nt)
#pragma unroll
            for (int r = 0; r < 4; ++r)
                Kh[(size_t)(m0 + wr + quad * 4 + r) * MD + n0 + nt * 16 + ln] =
                    (_Float16)acc[nt][r];
    } else {               // Q hi only (1-term QK)
#pragma unroll
        for (int nt = 0; nt < 4; ++nt)
#pragma unroll
            for (int r = 0; r < 4; ++r)
                Qh[(size_t)(m0 + wr + quad * 4 + r) * MD + n0 + nt * 16 + ln] =
                    (_Float16)acc[nt][r];
    }
}

// ---------------------------------------------------------------- MFMA flash attention (round-14 proven, unchanged)
template<int NSP>
__global__ __launch_bounds__(256)
void attn_mfma(const _Float16* __restrict__ Qhi,
               const _Float16* __restrict__ Kh_g, const _Float16* __restrict__ VTh_g,
               const _Float16* __restrict__ maskP, const unsigned char* __restrict__ mflag,
               _Float16* __restrict__ Opart, float* __restrict__ lpart)
{
    constexpr int KPS = SEQ / NSP;
    __shared__ _Float16 KhS[2][64 * LDSTR];   // [buf][key][d]
    __shared__ _Float16 VhS[2][64 * LDSTR];   // [buf][d][key]

    const int tid  = threadIdx.x;
    const int ln   = tid & 15;
    const int quad = (tid & 63) >> 4;
    const int wv   = tid >> 6;           // 0..3
    const int wr   = wv * 32;            // wave row base
    const int h    = blockIdx.y;
    const int m0   = blockIdx.x * 128;
    const int sp   = blockIdx.z;
    const int tbase = sp * KPS;

    const int srow = tid >> 2;           // 0..63
    const int scol = (tid & 3) << 4;     // 0,16,32,48

    // Q fragments: 2 rowsets x 2 k-chunks, hi only (B-operand)
    f16x8 qh[2][2];
#pragma unroll
    for (int rs = 0; rs < 2; ++rs)
#pragma unroll
        for (int ks = 0; ks < 2; ++ks) {
            const size_t off = (size_t)(m0 + wr + rs * 16 + ln) * MD + h * DH + ks * 32 + quad * 8;
            qh[rs][ks] = *(const f16x8*)&Qhi[off];
        }

    f32x4 O[2][4];
#pragma unroll
    for (int rs = 0; rs < 2; ++rs)
#pragma unroll
        for (int d = 0; d < 4; ++d)
            O[rs][d] = (f32x4){0.f, 0.f, 0.f, 0.f};
    float lsum[2] = {0.f, 0.f};

    // prologue: tile 0 K/V + flag into staging regs
    f16x8 rk0, rk1, rv0, rv1;
    unsigned char fcur, fnext;
    {
        const size_t gk = (size_t)(tbase + srow) * MD + h * DH + scol;
        const size_t gv = (size_t)(h * DH + srow) * SEQ + tbase + scol;
        rk0 = *(const f16x8*)&Kh_g[gk];
        rk1 = *(const f16x8*)&Kh_g[gk + 8];
        rv0 = *(const f16x8*)&VTh_g[gv];
        rv1 = *(const f16x8*)&VTh_g[gv + 8];
        fcur = mflag[blockIdx.x * 64 + (tbase >> 6)];
    }

    const int NT = KPS / 64;
    for (int t = 0; t < NT; ++t) {
        const int t0 = tbase + t * 64;
        _Float16* Kh = KhS[t & 1];
        _Float16* Vh = VhS[t & 1];

        // write current tile to LDS (regs loaded during previous iteration)
        *(f16x8*)&Kh[srow * LDSTR + scol]     = rk0;
        *(f16x8*)&Kh[srow * LDSTR + scol + 8] = rk1;
        *(f16x8*)&Vh[srow * LDSTR + scol]     = rv0;
        *(f16x8*)&Vh[srow * LDSTR + scol + 8] = rv1;

        // issue next-tile staging + flag loads (stay in flight across the barrier)
        const int t1 = tbase + ((t + 1 < NT) ? t + 1 : t) * 64;
        {
            const size_t gk = (size_t)(t1 + srow) * MD + h * DH + scol;
            const size_t gv = (size_t)(h * DH + srow) * SEQ + t1 + scol;
            rk0 = *(const f16x8*)&Kh_g[gk];
            rk1 = *(const f16x8*)&Kh_g[gk + 8];
            rv0 = *(const f16x8*)&VTh_g[gv];
            rv1 = *(const f16x8*)&VTh_g[gv + 8];
            fnext = mflag[blockIdx.x * 64 + (t1 >> 6)];
        }
        // mask fragments for CURRENT tile: only when tile has nonzero mask
        f16x8 bb[4];
        if (fcur) {
            const size_t mb = ((size_t)blockIdx.x * 64 + (size_t)(t0 >> 6)) * 8192 + (size_t)tid * 8;
#pragma unroll
            for (int c = 0; c < 4; ++c)
                bb[c] = *(const f16x8*)&maskP[mb + (size_t)c * 2048];
        } else {
#pragma unroll
            for (int c = 0; c < 4; ++c)
                bb[c] = (f16x8){0, 0, 0, 0, 0, 0, 0, 0};
        }

        // one barrier per tile: drain LDS writes only, NOT the global loads
        asm volatile("s_waitcnt lgkmcnt(0)" ::: "memory");
        __builtin_amdgcn_s_barrier();
        __builtin_amdgcn_sched_barrier(0);

        // S^T = K @ Q^T (1-term), K-frags from LDS
        f32x4 s[2][4];
#pragma unroll
        for (int rs = 0; rs < 2; ++rs)
#pragma unroll
            for (int st = 0; st < 4; ++st)
                s[rs][st] = (f32x4){0.f, 0.f, 0.f, 0.f};
        __builtin_amdgcn_s_setprio(1);
#pragma unroll
        for (int st = 0; st < 4; ++st)
#pragma unroll
            for (int ks = 0; ks < 2; ++ks) {
                const f16x8 ka = *(f16x8*)&Kh[(st * 16 + ln) * LDSTR + ks * 32 + quad * 8];
#pragma unroll
                for (int rs = 0; rs < 2; ++rs)
                    s[rs][st] = __builtin_amdgcn_mfma_f32_16x16x32_f16(ka, qh[rs][ks], s[rs][st], 0, 0, 0);
            }
        __builtin_amdgcn_s_setprio(0);

        // softmax numerator (fixed m=0, exp2-domain mask bias) + in-register
        // transpose of P to the PV A-fragment layout
        f16x8 pa[2][2];
#pragma unroll
        for (int rs = 0; rs < 2; ++rs) {
            unsigned int X01[4], X23[4];   // per st: packed (r0,r1) and (r2,r3)
#pragma unroll
            for (int st = 0; st < 4; ++st) {
                const int c  = (rs << 1) + (st >> 1);
                const int jb = (st & 1) << 2;
                const float e0 = exp2f(fmaf(s[rs][st][0], KSC, (float)bb[c][jb + 0]));
                const float e1 = exp2f(fmaf(s[rs][st][1], KSC, (float)bb[c][jb + 1]));
                const float e2 = exp2f(fmaf(s[rs][st][2], KSC, (float)bb[c][jb + 2]));
                const float e3 = exp2f(fmaf(s[rs][st][3], KSC, (float)bb[c][jb + 3]));
                lsum[rs] += (e0 + e1) + (e2 + e3);   // all same q-row: lane-local
                X01[st] = pkf16(e0, e1);
                X23[st] = pkf16(e2, e3);
            }
            // per 32-key chunk: word0/2 from X01(even,odd st), word1/3 from X23
#pragma unroll
            for (int ks = 0; ks < 2; ++ks) {
                unsigned int a0 = X01[2 * ks], b0 = X01[2 * ks + 1];
                unsigned int a1 = X23[2 * ks], b1 = X23[2 * ks + 1];
                pl32_swap(a0, b0); pl16_swap(a0, b0);   // a0=word0, b0=word2
                pl32_swap(a1, b1); pl16_swap(a1, b1);   // a1=word1, b1=word3
                union { unsigned int u[4]; f16x8 hv; } pw;
                pw.u[0] = a0; pw.u[1] = a1; pw.u[2] = b0; pw.u[3] = b1;
                pa[rs][ks] = pw.hv;
            }
        }

        // O += P @ V, V-frags from LDS
        __builtin_amdgcn_s_setprio(1);
#pragma unroll
        for (int dst = 0; dst < 4; ++dst)
#pragma unroll
            for (int ks = 0; ks < 2; ++ks) {
                const f16x8 vb = *(f16x8*)&Vh[(dst * 16 + ln) * LDSTR + ks * 32 + quad * 8];
#pragma unroll
                for (int rs = 0; rs < 2; ++rs)
                    O[rs][dst] = __builtin_amdgcn_mfma_f32_16x16x32_f16(pa[rs][ks], vb,
                                                                        O[rs][dst], 0, 0, 0);
            }
        __builtin_amdgcn_s_setprio(0);

        fcur = fnext;
    }

    // l reduction: lanes ln, ln+16, ln+32, ln+48 share a q-row
#pragma unroll
    for (int rs = 0; rs < 2; ++rs) {
        lsum[rs] += __shfl_xor(lsum[rs], 16);
        lsum[rs] += __shfl_xor(lsum[rs], 32);
    }

    // epilogue: store UNNORMALIZED partial O (fp16) + partial l
    _Float16* Op = Opart + (size_t)sp * SEQ * MD;
    float*    lp = lpart + ((size_t)sp * NH + h) * SEQ;
    if ((tid & 48) == 0) {   // quad==0 lanes hold full sums for q = ln
#pragma unroll
        for (int rs = 0; rs < 2; ++rs)
            lp[m0 + wr + rs * 16 + ln] = lsum[rs];
    }
#pragma unroll
    for (int rs = 0; rs < 2; ++rs)
#pragma unroll
        for (int r = 0; r < 4; ++r) {
            const int row = m0 + wr + rs * 16 + quad * 4 + r;
#pragma unroll
            for (int dst = 0; dst < 4; ++dst)
                Op[(size_t)row * MD + h * DH + dst * 16 + ln] = (_Float16)O[rs][dst][r];
        }
}

// ---------------------------------------------------------------- output GEMM with fused split-combine
// (round-13 proven: 1-term A, W via LDS from pre-transposed woT)
template<int NSP>
__global__ __launch_bounds__(256)
void gemm_out(const _Float16* __restrict__ Opart, const float* __restrict__ lpart,
              const _Float16* __restrict__ WTo, const float* __restrict__ bo,
              float* __restrict__ out)
{
    const size_t NE = (size_t)SEQ * MD;
    __shared__ _Float16 Ash[64 * LDSTR], Wsh[64 * LDSTR];

    const int tid  = threadIdx.x;
    const int ln   = tid & 15;
    const int quad = (tid & 63) >> 4;
    const int wv_  = tid >> 6;
    const int wr   = wv_ * 16;
    const int m0   = blockIdx.x * 64;
    const int n0   = blockIdx.y * 64;
    const int srow = tid >> 2;
    const int scol = (tid & 3) << 4;

    f32x4 acc[4] = {{0.f,0.f,0.f,0.f},{0.f,0.f,0.f,0.f},
                    {0.f,0.f,0.f,0.f},{0.f,0.f,0.f,0.f}};

    for (int k0 = 0; k0 < MD; k0 += 64) {
        const int row = m0 + srow;
        const int h   = (k0 + scol) >> 6;
        float l = 0.f;
#pragma unroll
        for (int sp = 0; sp < NSP; ++sp)
            l += lpart[((size_t)sp * NH + h) * SEQ + row];
        const float inv = 1.0f / l;

        float cx[16] = {0.f};
#pragma unroll
        for (int sp = 0; sp < NSP; ++sp) {
            const size_t go = (size_t)sp * NE + (size_t)row * MD + k0 + scol;
            const f16x8 o0 = *(const f16x8*)&Opart[go];
            const f16x8 o1 = *(const f16x8*)&Opart[go + 8];
#pragma unroll
            for (int j = 0; j < 8; ++j) { cx[j] += (float)o0[j]; cx[8 + j] += (float)o1[j]; }
        }
        const size_t gwt = (size_t)(n0 + srow) * MD + k0 + scol;
        const f16x8 w0 = *(const f16x8*)&WTo[gwt];
        const f16x8 w1 = *(const f16x8*)&WTo[gwt + 8];
        f16x8 ah[2];
#pragma unroll
        for (int half = 0; half < 2; ++half)
#pragma unroll
            for (int j = 0; j < 8; ++j)
                ah[half][j] = (_Float16)(cx[half * 8 + j] * inv);
        __syncthreads();
        *(f16x8*)&Ash[srow * LDSTR + scol]     = ah[0];
        *(f16x8*)&Ash[srow * LDSTR + scol + 8] = ah[1];
        *(f16x8*)&Wsh[srow * LDSTR + scol]     = w0;
        *(f16x8*)&Wsh[srow * LDSTR + scol + 8] = w1;
        __syncthreads();

#pragma unroll
        for (int ks = 0; ks < 2; ++ks) {
            const f16x8 fa = *(f16x8*)&Ash[(wr + ln) * LDSTR + ks * 32 + quad * 8];
#pragma unroll
            for (int nt = 0; nt < 4; ++nt) {
                const f16x8 fb = *(f16x8*)&Wsh[(nt * 16 + ln) * LDSTR + ks * 32 + quad * 8];
                acc[nt] = __builtin_amdgcn_mfma_f32_16x16x32_f16(fa, fb, acc[nt], 0, 0, 0);
            }
        }
    }

#pragma unroll
    for (int nt = 0; nt < 4; ++nt) {
        const float bb = bo[n0 + nt * 16 + ln];
#pragma unroll
        for (int r = 0; r < 4; ++r)
            out[(size_t)(m0 + wr + quad * 4 + r) * MD + n0 + nt * 16 + ln] =
                acc[nt][r] + bb;
    }
}

// ---------------------------------------------------------------- launch
extern "C" void kernel_launch(void* const* d_in, const int* in_sizes, int n_in,
                              void* d_out, int out_size, void* d_ws, size_t ws_size,
                              hipStream_t stream)
{
    const float* q    = (const float*)d_in[0];
    const float* k    = (const float*)d_in[1];
    const float* v    = (const float*)d_in[2];
    const float* mask = (const float*)d_in[3];
    const float* wq   = (const float*)d_in[4];
    const float* wk   = (const float*)d_in[5];
    const float* wv   = (const float*)d_in[6];
    const float* wo   = (const float*)d_in[7];
    const float* bo   = (const float*)d_in[8];
    float* out = (float*)d_out;

    const size_t NE = (size_t)SEQ * MD;   // 2M elements
    _Float16* base = (_Float16*)d_ws;
    _Float16* Qh  = base;                 // NE
    _Float16* Kh  = base + 2 * NE;        // NE
    _Float16* VTh = base + 3 * NE;        // NE ([MD][SEQ])

    // NSPLIT=4 layout needs (16NE + MD^2) f16 + 4*NH*SEQ f32 + flags = ~65 MiB.
    const size_t NEED4 = ((size_t)16 * NE + (size_t)MD * MD) * sizeof(_Float16)
                       + (size_t)4 * NH * SEQ * sizeof(float) + 4096;
    const bool big = (ws_size >= NEED4);

    _Float16* Opart = base + 4 * NE;                       // NSP*NE
    _Float16* WT3   = base + 4 * NE;                       // overlaps Opart (dead before attn)
    _Float16* maskP = big ? (base + 8 * NE) : (base + 6 * NE);   // 8NE (SEQ*SEQ f16)
    _Float16* woT   = big ? (base + 16 * NE) : (base + 14 * NE); // MD*MD
    float*    lpart = (float*)(woT + (size_t)MD * MD);     // NSP*NH*SEQ fp32
    unsigned char* mflag = (unsigned char*)(lpart + (size_t)(big ? 4 : 2) * NH * SEQ); // 2048 B

    // 0. weight transposes (f32 [k][n] -> f16 [n][k])
    prep_wt<<<dim3(8, 8, 4), 256, 0, stream>>>(wq, wk, wv, wo, WT3, woT);

    // 1. q/k/v projections (z=0..2) + mask scan/flag (z=3)
    proj3m<<<dim3(SEQ / 64, MD / 64, 4), 256, 0, stream>>>(q, k, v, mask, WT3,
                                                           Qh, Kh, VTh, maskP, mflag);

    // 2+3. attention (key-split) + output projection, split count by ws capacity
    if (big) {
        attn_mfma<4><<<dim3(SEQ / 128, NH, 4), 256, 0, stream>>>(Qh, Kh, VTh, maskP, mflag,
                                                                 Opart, lpart);
        gemm_out<4><<<dim3(SEQ / 64, MD / 64), 256, 0, stream>>>(Opart, lpart, woT, bo, out);
    } else {
        attn_mfma<2><<<dim3(SEQ / 128, NH, 2), 256, 0, stream>>>(Qh, Kh, VTh, maskP, mflag,
                                                                 Opart, lpart);
        gemm_out<2><<<dim3(SEQ / 64, MD / 64), 256, 0, stream>>>(Opart, lpart, woT, bo, out);
    }
}

// Round 16
// 222.054 us; speedup vs baseline: 1.0048x; 1.0048x over previous
//
#include <hip/hip_runtime.h>
#include <math.h>

#define MD   512
#define NH   8
#define DH   64
#define SEQ  4096

typedef _Float16 f16x8 __attribute__((ext_vector_type(8)));
typedef _Float16 f16x4 __attribute__((ext_vector_type(4)));
typedef float    f32x4 __attribute__((ext_vector_type(4)));

#define LDSTR 72   // f16 row stride: 144 B, 16B-aligned, 2-way bank aliasing max
#define KMK   (-1.0e9f * 1.4426950408889634f)   // mask -> exp2-domain bias
#define KSC   (0.125f * 1.4426950408889634f)    // 1/sqrt(64) * log2(e)

// pack two f32 -> one u32 of two f16 (RTZ)
static __device__ __forceinline__ unsigned int pkf16(float a, float b) {
    auto t = __builtin_amdgcn_cvt_pkrtz(a, b);   // __fp16 ext_vector(2)
    return __builtin_bit_cast(unsigned int, t);
}
// in-place lane-group swaps (gfx950): both operands modified
static __device__ __forceinline__ void pl32_swap(unsigned int& a, unsigned int& b) {
    asm("v_permlane32_swap_b32 %0, %1" : "+v"(a), "+v"(b));
}
static __device__ __forceinline__ void pl16_swap(unsigned int& a, unsigned int& b) {
    asm("v_permlane16_swap_b32 %0, %1" : "+v"(a), "+v"(b));
}

// ---------------------------------------------------------------- prep_wt (round-5 proven):
// transpose wq/wk/wv (f32 [k][n]) -> WT3 f16 [n][k] and wo -> woT.
__global__ __launch_bounds__(256)
void prep_wt(const float* __restrict__ wq, const float* __restrict__ wk,
             const float* __restrict__ wv, const float* __restrict__ wo,
             _Float16* __restrict__ WT3, _Float16* __restrict__ woT)
{
    __shared__ float t[64][65];
    const int z = blockIdx.z;
    const float* W = (z == 0) ? wq : (z == 1) ? wk : (z == 2) ? wv : wo;
    _Float16* WTz = (z < 3) ? (WT3 + (size_t)z * MD * MD) : woT;
    const int k0 = blockIdx.x * 64, n0 = blockIdx.y * 64;
    const int c = threadIdx.x & 63, rbase = (threadIdx.x >> 6) * 16;
#pragma unroll
    for (int i = 0; i < 16; ++i)
        t[rbase + i][c] = W[(size_t)(k0 + rbase + i) * MD + n0 + c];
    __syncthreads();
#pragma unroll
    for (int i = 0; i < 16; ++i)
        WTz[(size_t)(n0 + rbase + i) * MD + k0 + c] = (_Float16)t[c][rbase + i];
}

// ---------------------------------------------------------------- proj3m:
// Grid (SEQ/64, MD/128, 4). z=0..2: 64x128-tile GEMM slices (A re-read 8x -> 4x);
// z=3: wave-autonomous mask scan (2 tiles/wave) -> nonzero FLAG + maskP (rare).
// W staged via LDS (proven); 1-term A (round-13 proven). Per-output arithmetic
// identical to round 15 -> bit-identical results.
__global__ __launch_bounds__(256)
void proj3m(const float* __restrict__ q, const float* __restrict__ k,
            const float* __restrict__ v, const float* __restrict__ mask,
            const _Float16* __restrict__ WT3,
            _Float16* __restrict__ Qh,
            _Float16* __restrict__ Kh, _Float16* __restrict__ VTh,
            _Float16* __restrict__ maskP, unsigned char* __restrict__ mflag)
{
    __shared__ _Float16 SH[192 * LDSTR];   // GEMM: Ash(64)|Wsh(128); mask: 4x 32-row patch

    const int z   = blockIdx.z;
    const int tid = threadIdx.x;
    const int ln   = tid & 15;
    const int quad = (tid & 63) >> 4;
    const int wv_  = tid >> 6;

    if (z == 3) {   // ---- mask scan: ONE WAVE per 128x64 idx-tile, 2 tiles/wave
        const int l16 = tid & 15;
        const int r4  = (tid & 63) >> 4;
#pragma unroll 1
        for (int i = 0; i < 2; ++i) {
            const int idx = ((blockIdx.y * 64 + blockIdx.x) << 3) + wv_ * 2 + i; // 0..2047
            const int bx  = idx >> 6;     // 128-row tile
            const int tg  = idx & 63;     // 64-col tile
            const float* basep = mask + (size_t)(bx * 128) * SEQ + tg * 64 + l16 * 4;

            // common path: scan 128 rows with float4 loads, flag only
            int nz = 0;
#pragma unroll 1
            for (int sec = 0; sec < 4; ++sec) {
                float4 mm[8];
#pragma unroll
                for (int r = 0; r < 8; ++r)
                    mm[r] = *(const float4*)(basep + (size_t)(sec * 32 + r * 4 + r4) * SEQ);
#pragma unroll
                for (int r = 0; r < 8; ++r)
                    nz |= (mm[r].x != 0.f) | (mm[r].y != 0.f) |
                          (mm[r].z != 0.f) | (mm[r].w != 0.f);
            }
            const bool has = (__ballot(nz) != 0ULL);
            if ((tid & 63) == 0) mflag[idx] = has ? 1 : 0;

            if (has) {   // rare path: emit permuted maskP via wave-private LDS patch
                _Float16* T = SH + wv_ * (32 * LDSTR);   // 32x72 f16 patch
                _Float16* outp = maskP + (size_t)idx * 8192;
#pragma unroll 1
                for (int sec = 0; sec < 4; ++sec) {
#pragma unroll
                    for (int r = 0; r < 8; ++r) {
                        const int rr = r * 4 + r4;
                        const float4 mm = *(const float4*)(basep + (size_t)(sec * 32 + rr) * SEQ);
                        f16x4 hv;
                        hv[0] = (_Float16)(mm.x * KMK); hv[1] = (_Float16)(mm.y * KMK);
                        hv[2] = (_Float16)(mm.z * KMK); hv[3] = (_Float16)(mm.w * KMK);
                        *(f16x4*)&T[rr * LDSTR + l16 * 4] = hv;
                    }
                    asm volatile("s_waitcnt lgkmcnt(0)" ::: "memory");
                    __builtin_amdgcn_sched_barrier(0);
#pragma unroll
                    for (int c = 0; c < 4; ++c) {
                        const int rho = (c >> 1) * 16 + l16;
                        const int cb  = (c & 1) * 32 + r4 * 4;
                        const f16x4 lo = *(const f16x4*)&T[rho * LDSTR + cb];
                        const f16x4 hi = *(const f16x4*)&T[rho * LDSTR + cb + 16];
                        f16x8 hv;
                        hv[0] = lo[0]; hv[1] = lo[1]; hv[2] = lo[2]; hv[3] = lo[3];
                        hv[4] = hi[0]; hv[5] = hi[1]; hv[6] = hi[2]; hv[7] = hi[3];
                        *(f16x8*)&outp[(size_t)c * 2048 +
                                       (size_t)(sec * 64 + (tid & 63)) * 8] = hv;
                    }
                    asm volatile("s_waitcnt lgkmcnt(0)" ::: "memory");
                    __builtin_amdgcn_sched_barrier(0);
                }
            }
        }
        return;
    }

    _Float16* Ash = SH;                    // 64 rows
    _Float16* Wsh = SH + 64 * LDSTR;       // 128 rows

    const float* A32 = (z == 0) ? q : (z == 1) ? k : v;
    const _Float16* WTz = WT3 + (size_t)z * MD * MD;

    const int wr   = wv_ * 16;
    const int m0   = blockIdx.x * 64;
    const int n0   = blockIdx.y * 128;
    const int srow = tid >> 2;          // 0..63  (A staging)
    const int scol = (tid & 3) << 4;    // 0,16,32,48
    const int wrow = tid >> 1;          // 0..127 (W staging)
    const int wcol = (tid & 1) << 5;    // 0,32

    f32x4 acc[8];
#pragma unroll
    for (int nt = 0; nt < 8; ++nt) acc[nt] = (f32x4){0.f, 0.f, 0.f, 0.f};

    for (int k0 = 0; k0 < MD; k0 += 64) {
        const size_t ga  = (size_t)(m0 + srow) * MD + k0 + scol;
        const size_t gwt = (size_t)(n0 + wrow) * MD + k0 + wcol;
        float a[16];
#pragma unroll
        for (int j = 0; j < 4; ++j) {
            const float4 xa = *(const float4*)&A32[ga + j * 4];
            a[j*4+0] = xa.x; a[j*4+1] = xa.y; a[j*4+2] = xa.z; a[j*4+3] = xa.w;
        }
        f16x8 w[4];
#pragma unroll
        for (int j = 0; j < 4; ++j)
            w[j] = *(const f16x8*)&WTz[gwt + j * 8];
        f16x8 ah[2];
#pragma unroll
        for (int half = 0; half < 2; ++half)
#pragma unroll
            for (int j = 0; j < 8; ++j)
                ah[half][j] = (_Float16)a[half * 8 + j];
        __syncthreads();
        *(f16x8*)&Ash[srow * LDSTR + scol]     = ah[0];
        *(f16x8*)&Ash[srow * LDSTR + scol + 8] = ah[1];
#pragma unroll
        for (int j = 0; j < 4; ++j)
            *(f16x8*)&Wsh[wrow * LDSTR + wcol + j * 8] = w[j];   // [n][k]
        __syncthreads();

#pragma unroll
        for (int ks = 0; ks < 2; ++ks) {
            const f16x8 fa = *(f16x8*)&Ash[(wr + ln) * LDSTR + ks * 32 + quad * 8];
#pragma unroll
            for (int nt = 0; nt < 8; ++nt) {
                const f16x8 fb = *(f16x8*)&Wsh[(nt * 16 + ln) * LDSTR + ks * 32 + quad * 8];
                acc[nt] = __builtin_amdgcn_mfma_f32_16x16x32_f16(fa, fb, acc[nt], 0, 0, 0);
            }
        }
    }

    if (z == 2) {   // V hi, transposed [MD][SEQ]
#pragma unroll
        for (int nt = 0; nt < 8; ++nt)
#pragma unroll
            for (int r = 0; r < 4; ++r)
                VTh[(size_t)(n0 + nt * 16 + ln) * SEQ + m0 + wr + quad * 4 + r] =
                    (_Float16)acc[nt][r];
    } else if (z == 1) {   // K hi only
#pragma unroll
        for (int nt = 0; nt < 8; ++nt)
#pragma unroll
            for (int r = 0; r < 4; ++r)
                Kh[(size_t)(m0 + wr + quad * 4 + r) * MD + n0 + nt * 16 + ln] =
                    (_Float16)acc[nt][r];
    } else {               // Q hi only (1-term QK)
#pragma unroll
        for (int nt = 0; nt < 8; ++nt)
#pragma unroll
            for (int r = 0; r < 4; ++r)
                Qh[(size_t)(m0 + wr + quad * 4 + r) * MD + n0 + nt * 16 + ln] =
                    (_Float16)acc[nt][r];
    }
}

// ---------------------------------------------------------------- MFMA flash attention (round-14/15 proven, unchanged)
template<int NSP>
__global__ __launch_bounds__(256)
void attn_mfma(const _Float16* __restrict__ Qhi,
               const _Float16* __restrict__ Kh_g, const _Float16* __restrict__ VTh_g,
               const _Float16* __restrict__ maskP, const unsigned char* __restrict__ mflag,
               _Float16* __restrict__ Opart, float* __restrict__ lpart)
{
    constexpr int KPS = SEQ / NSP;
    __shared__ _Float16 KhS[2][64 * LDSTR];   // [buf][key][d]
    __shared__ _Float16 VhS[2][64 * LDSTR];   // [buf][d][key]

    const int tid  = threadIdx.x;
    const int ln   = tid & 15;
    const int quad = (tid & 63) >> 4;
    const int wv   = tid >> 6;           // 0..3
    const int wr   = wv * 32;            // wave row base
    const int h    = blockIdx.y;
    const int m0   = blockIdx.x * 128;
    const int sp   = blockIdx.z;
    const int tbase = sp * KPS;

    const int srow = tid >> 2;           // 0..63
    const int scol = (tid & 3) << 4;     // 0,16,32,48

    // Q fragments: 2 rowsets x 2 k-chunks, hi only (B-operand)
    f16x8 qh[2][2];
#pragma unroll
    for (int rs = 0; rs < 2; ++rs)
#pragma unroll
        for (int ks = 0; ks < 2; ++ks) {
            const size_t off = (size_t)(m0 + wr + rs * 16 + ln) * MD + h * DH + ks * 32 + quad * 8;
            qh[rs][ks] = *(const f16x8*)&Qhi[off];
        }

    f32x4 O[2][4];
#pragma unroll
    for (int rs = 0; rs < 2; ++rs)
#pragma unroll
        for (int d = 0; d < 4; ++d)
            O[rs][d] = (f32x4){0.f, 0.f, 0.f, 0.f};
    float lsum[2] = {0.f, 0.f};

    // prologue: tile 0 K/V + flag into staging regs
    f16x8 rk0, rk1, rv0, rv1;
    unsigned char fcur, fnext;
    {
        const size_t gk = (size_t)(tbase + srow) * MD + h * DH + scol;
        const size_t gv = (size_t)(h * DH + srow) * SEQ + tbase + scol;
        rk0 = *(const f16x8*)&Kh_g[gk];
        rk1 = *(const f16x8*)&Kh_g[gk + 8];
        rv0 = *(const f16x8*)&VTh_g[gv];
        rv1 = *(const f16x8*)&VTh_g[gv + 8];
        fcur = mflag[blockIdx.x * 64 + (tbase >> 6)];
    }

    const int NT = KPS / 64;
    for (int t = 0; t < NT; ++t) {
        const int t0 = tbase + t * 64;
        _Float16* Kh = KhS[t & 1];
        _Float16* Vh = VhS[t & 1];

        // write current tile to LDS (regs loaded during previous iteration)
        *(f16x8*)&Kh[srow * LDSTR + scol]     = rk0;
        *(f16x8*)&Kh[srow * LDSTR + scol + 8] = rk1;
        *(f16x8*)&Vh[srow * LDSTR + scol]     = rv0;
        *(f16x8*)&Vh[srow * LDSTR + scol + 8] = rv1;

        // issue next-tile staging + flag loads (stay in flight across the barrier)
        const int t1 = tbase + ((t + 1 < NT) ? t + 1 : t) * 64;
        {
            const size_t gk = (size_t)(t1 + srow) * MD + h * DH + scol;
            const size_t gv = (size_t)(h * DH + srow) * SEQ + t1 + scol;
            rk0 = *(const f16x8*)&Kh_g[gk];
            rk1 = *(const f16x8*)&Kh_g[gk + 8];
            rv0 = *(const f16x8*)&VTh_g[gv];
            rv1 = *(const f16x8*)&VTh_g[gv + 8];
            fnext = mflag[blockIdx.x * 64 + (t1 >> 6)];
        }
        // mask fragments for CURRENT tile: only when tile has nonzero mask
        f16x8 bb[4];
        if (fcur) {
            const size_t mb = ((size_t)blockIdx.x * 64 + (size_t)(t0 >> 6)) * 8192 + (size_t)tid * 8;
#pragma unroll
            for (int c = 0; c < 4; ++c)
                bb[c] = *(const f16x8*)&maskP[mb + (size_t)c * 2048];
        } else {
#pragma unroll
            for (int c = 0; c < 4; ++c)
                bb[c] = (f16x8){0, 0, 0, 0, 0, 0, 0, 0};
        }

        // one barrier per tile: drain LDS writes only, NOT the global loads
        asm volatile("s_waitcnt lgkmcnt(0)" ::: "memory");
        __builtin_amdgcn_s_barrier();
        __builtin_amdgcn_sched_barrier(0);

        // S^T = K @ Q^T (1-term), K-frags from LDS
        f32x4 s[2][4];
#pragma unroll
        for (int rs = 0; rs < 2; ++rs)
#pragma unroll
            for (int st = 0; st < 4; ++st)
                s[rs][st] = (f32x4){0.f, 0.f, 0.f, 0.f};
        __builtin_amdgcn_s_setprio(1);
#pragma unroll
        for (int st = 0; st < 4; ++st)
#pragma unroll
            for (int ks = 0; ks < 2; ++ks) {
                const f16x8 ka = *(f16x8*)&Kh[(st * 16 + ln) * LDSTR + ks * 32 + quad * 8];
#pragma unroll
                for (int rs = 0; rs < 2; ++rs)
                    s[rs][st] = __builtin_amdgcn_mfma_f32_16x16x32_f16(ka, qh[rs][ks], s[rs][st], 0, 0, 0);
            }
        __builtin_amdgcn_s_setprio(0);

        // softmax numerator (fixed m=0, exp2-domain mask bias) + in-register
        // transpose of P to the PV A-fragment layout
        f16x8 pa[2][2];
#pragma unroll
        for (int rs = 0; rs < 2; ++rs) {
            unsigned int X01[4], X23[4];   // per st: packed (r0,r1) and (r2,r3)
#pragma unroll
            for (int st = 0; st < 4; ++st) {
                const int c  = (rs << 1) + (st >> 1);
                const int jb = (st & 1) << 2;
                const float e0 = exp2f(fmaf(s[rs][st][0], KSC, (float)bb[c][jb + 0]));
                const float e1 = exp2f(fmaf(s[rs][st][1], KSC, (float)bb[c][jb + 1]));
                const float e2 = exp2f(fmaf(s[rs][st][2], KSC, (float)bb[c][jb + 2]));
                const float e3 = exp2f(fmaf(s[rs][st][3], KSC, (float)bb[c][jb + 3]));
                lsum[rs] += (e0 + e1) + (e2 + e3);   // all same q-row: lane-local
                X01[st] = pkf16(e0, e1);
                X23[st] = pkf16(e2, e3);
            }
            // per 32-key chunk: word0/2 from X01(even,odd st), word1/3 from X23
#pragma unroll
            for (int ks = 0; ks < 2; ++ks) {
                unsigned int a0 = X01[2 * ks], b0 = X01[2 * ks + 1];
                unsigned int a1 = X23[2 * ks], b1 = X23[2 * ks + 1];
                pl32_swap(a0, b0); pl16_swap(a0, b0);   // a0=word0, b0=word2
                pl32_swap(a1, b1); pl16_swap(a1, b1);   // a1=word1, b1=word3
                union { unsigned int u[4]; f16x8 hv; } pw;
                pw.u[0] = a0; pw.u[1] = a1; pw.u[2] = b0; pw.u[3] = b1;
                pa[rs][ks] = pw.hv;
            }
        }

        // O += P @ V, V-frags from LDS
        __builtin_amdgcn_s_setprio(1);
#pragma unroll
        for (int dst = 0; dst < 4; ++dst)
#pragma unroll
            for (int ks = 0; ks < 2; ++ks) {
                const f16x8 vb = *(f16x8*)&Vh[(dst * 16 + ln) * LDSTR + ks * 32 + quad * 8];
#pragma unroll
                for (int rs = 0; rs < 2; ++rs)
                    O[rs][dst] = __builtin_amdgcn_mfma_f32_16x16x32_f16(pa[rs][ks], vb,
                                                                        O[rs][dst], 0, 0, 0);
            }
        __builtin_amdgcn_s_setprio(0);

        fcur = fnext;
    }

    // l reduction: lanes ln, ln+16, ln+32, ln+48 share a q-row
#pragma unroll
    for (int rs = 0; rs < 2; ++rs) {
        lsum[rs] += __shfl_xor(lsum[rs], 16);
        lsum[rs] += __shfl_xor(lsum[rs], 32);
    }

    // epilogue: store UNNORMALIZED partial O (fp16) + partial l
    _Float16* Op = Opart + (size_t)sp * SEQ * MD;
    float*    lp = lpart + ((size_t)sp * NH + h) * SEQ;
    if ((tid & 48) == 0) {   // quad==0 lanes hold full sums for q = ln
#pragma unroll
        for (int rs = 0; rs < 2; ++rs)
            lp[m0 + wr + rs * 16 + ln] = lsum[rs];
    }
#pragma unroll
    for (int rs = 0; rs < 2; ++rs)
#pragma unroll
        for (int r = 0; r < 4; ++r) {
            const int row = m0 + wr + rs * 16 + quad * 4 + r;
#pragma unroll
            for (int dst = 0; dst < 4; ++dst)
                Op[(size_t)row * MD + h * DH + dst * 16 + ln] = (_Float16)O[rs][dst][r];
        }
}

// ---------------------------------------------------------------- output GEMM with fused split-combine
// 64x128 tile (Opart re-read 8x -> 4x); 1-term A; W via LDS from woT.
template<int NSP>
__global__ __launch_bounds__(256)
void gemm_out(const _Float16* __restrict__ Opart, const float* __restrict__ lpart,
              const _Float16* __restrict__ WTo, const float* __restrict__ bo,
              float* __restrict__ out)
{
    const size_t NE = (size_t)SEQ * MD;
    __shared__ _Float16 Ash[64 * LDSTR], Wsh[128 * LDSTR];

    const int tid  = threadIdx.x;
    const int ln   = tid & 15;
    const int quad = (tid & 63) >> 4;
    const int wv_  = tid >> 6;
    const int wr   = wv_ * 16;
    const int m0   = blockIdx.x * 64;
    const int n0   = blockIdx.y * 128;
    const int srow = tid >> 2;
    const int scol = (tid & 3) << 4;
    const int wrow = tid >> 1;          // 0..127
    const int wcol = (tid & 1) << 5;    // 0,32

    f32x4 acc[8];
#pragma unroll
    for (int nt = 0; nt < 8; ++nt) acc[nt] = (f32x4){0.f, 0.f, 0.f, 0.f};

    for (int k0 = 0; k0 < MD; k0 += 64) {
        const int row = m0 + srow;
        const int h   = (k0 + scol) >> 6;
        float l = 0.f;
#pragma unroll
        for (int sp = 0; sp < NSP; ++sp)
            l += lpart[((size_t)sp * NH + h) * SEQ + row];
        const float inv = 1.0f / l;

        float cx[16] = {0.f};
#pragma unroll
        for (int sp = 0; sp < NSP; ++sp) {
            const size_t go = (size_t)sp * NE + (size_t)row * MD + k0 + scol;
            const f16x8 o0 = *(const f16x8*)&Opart[go];
            const f16x8 o1 = *(const f16x8*)&Opart[go + 8];
#pragma unroll
            for (int j = 0; j < 8; ++j) { cx[j] += (float)o0[j]; cx[8 + j] += (float)o1[j]; }
        }
        const size_t gwt = (size_t)(n0 + wrow) * MD + k0 + wcol;
        f16x8 w[4];
#pragma unroll
        for (int j = 0; j < 4; ++j)
            w[j] = *(const f16x8*)&WTo[gwt + j * 8];
        f16x8 ah[2];
#pragma unroll
        for (int half = 0; half < 2; ++half)
#pragma unroll
            for (int j = 0; j < 8; ++j)
                ah[half][j] = (_Float16)(cx[half * 8 + j] * inv);
        __syncthreads();
        *(f16x8*)&Ash[srow * LDSTR + scol]     = ah[0];
        *(f16x8*)&Ash[srow * LDSTR + scol + 8] = ah[1];
#pragma unroll
        for (int j = 0; j < 4; ++j)
            *(f16x8*)&Wsh[wrow * LDSTR + wcol + j * 8] = w[j];
        __syncthreads();

#pragma unroll
        for (int ks = 0; ks < 2; ++ks) {
            const f16x8 fa = *(f16x8*)&Ash[(wr + ln) * LDSTR + ks * 32 + quad * 8];
#pragma unroll
            for (int nt = 0; nt < 8; ++nt) {
                const f16x8 fb = *(f16x8*)&Wsh[(nt * 16 + ln) * LDSTR + ks * 32 + quad * 8];
                acc[nt] = __builtin_amdgcn_mfma_f32_16x16x32_f16(fa, fb, acc[nt], 0, 0, 0);
            }
        }
    }

#pragma unroll
    for (int nt = 0; nt < 8; ++nt) {
        const float bb = bo[n0 + nt * 16 + ln];
#pragma unroll
        for (int r = 0; r < 4; ++r)
            out[(size_t)(m0 + wr + quad * 4 + r) * MD + n0 + nt * 16 + ln] =
                acc[nt][r] + bb;
    }
}

// ---------------------------------------------------------------- launch
extern "C" void kernel_launch(void* const* d_in, const int* in_sizes, int n_in,
                              void* d_out, int out_size, void* d_ws, size_t ws_size,
                              hipStream_t stream)
{
    const float* q    = (const float*)d_in[0];
    const float* k    = (const float*)d_in[1];
    const float* v    = (const float*)d_in[2];
    const float* mask = (const float*)d_in[3];
    const float* wq   = (const float*)d_in[4];
    const float* wk   = (const float*)d_in[5];
    const float* wv   = (const float*)d_in[6];
    const float* wo   = (const float*)d_in[7];
    const float* bo   = (const float*)d_in[8];
    float* out = (float*)d_out;

    const size_t NE = (size_t)SEQ * MD;   // 2M elements
    _Float16* base = (_Float16*)d_ws;
    _Float16* Qh  = base;                 // NE
    _Float16* Kh  = base + 2 * NE;        // NE
    _Float16* VTh = base + 3 * NE;        // NE ([MD][SEQ])

    // NSPLIT=4 layout needs (16NE + MD^2) f16 + 4*NH*SEQ f32 + flags = ~65 MiB.
    const size_t NEED4 = ((size_t)16 * NE + (size_t)MD * MD) * sizeof(_Float16)
                       + (size_t)4 * NH * SEQ * sizeof(float) + 4096;
    const bool big = (ws_size >= NEED4);

    _Float16* Opart = base + 4 * NE;                       // NSP*NE
    _Float16* WT3   = base + 4 * NE;                       // overlaps Opart (dead before attn)
    _Float16* maskP = big ? (base + 8 * NE) : (base + 6 * NE);   // 8NE (SEQ*SEQ f16)
    _Float16* woT   = big ? (base + 16 * NE) : (base + 14 * NE); // MD*MD
    float*    lpart = (float*)(woT + (size_t)MD * MD);     // NSP*NH*SEQ fp32
    unsigned char* mflag = (unsigned char*)(lpart + (size_t)(big ? 4 : 2) * NH * SEQ); // 2048 B

    // 0. weight transposes (f32 [k][n] -> f16 [n][k])
    prep_wt<<<dim3(8, 8, 4), 256, 0, stream>>>(wq, wk, wv, wo, WT3, woT);

    // 1. q/k/v projections (z=0..2, 64x128 tiles) + mask scan/flag (z=3)
    proj3m<<<dim3(SEQ / 64, MD / 128, 4), 256, 0, stream>>>(q, k, v, mask, WT3,
                                                            Qh, Kh, VTh, maskP, mflag);

    // 2+3. attention (key-split) + output projection, split count by ws capacity
    if (big) {
        attn_mfma<4><<<dim3(SEQ / 128, NH, 4), 256, 0, stream>>>(Qh, Kh, VTh, maskP, mflag,
                                                                 Opart, lpart);
        gemm_out<4><<<dim3(SEQ / 64, MD / 128), 256, 0, stream>>>(Opart, lpart, woT, bo, out);
    } else {
        attn_mfma<2><<<dim3(SEQ / 128, NH, 2), 256, 0, stream>>>(Qh, Kh, VTh, maskP, mflag,
                                                                 Opart, lpart);
        gemm_out<2><<<dim3(SEQ / 64, MD / 128), 256, 0, stream>>>(Opart, lpart, woT, bo, out);
    }
}